// Round 7
// baseline (1044.668 us; speedup 1.0000x reference)
//
#include <hip/hip_runtime.h>

// Problem constants (from reference setup_inputs):
//   x: (4,4096,1024) fp32 -> M=16384, dim=1024, hidden=4096, rank=16
//   w_fc: (4096,1024), w_proj: (1024,4096), u:(4096,16), v:(16,1024), fast_b:(16,16), gate scalar
// out: (16384,1024) fp32
//
// R5:  128^2 tile, BK=64, multi-block/CU -> 179 us/gemm.
// R6/R7/R10: 256^2, 8 waves(128x64/wave), 3 different schedules ALL converge
//     at 151-157 us, MfmaUtil 37-39%. Decomposition: LDS 1500 + DMA 500 +
//     MFMA 2060 + ~1600 exposed-wait cyc/K-tile. 128KB LDS -> 1 block/CU ->
//     no TLP to hide waits; schedules can't fix it (barrier-locked waves).
// R11: 4 waves x 128x128, 1 wave/SIMD -> 246 us, MfmaUtil 24%, VGPR capped.
//     FALSIFIED: zero TLP exposes every latency; acc+frags bust VGPR budget.
// R12: keep 128x64/wave fragment geometry; re-cut block to 256x128, 4 waves,
//     BK=32, LDS 48KB dbuf -> 3 blocks/CU (12 waves, 3/SIMD). Cross-BLOCK
//     anti-phase supplies the overlap (m114 mechanism; what R5 had).
//     GEMM2 grid 256->512 blocks (co-residency for the K-heavy GEMM too).
//     1 barrier/K-tile: stage(nxt) | 12 ds_read | 32 MFMA | vmcnt(0) | bar.
//     Swizzle re-derived for 32-elem rows: pos = quad^((lr>>1)&3); staging
//     k-chunk (tid&3)^((tid>>3)&3) const/thread; 2-way max (free, m136).

typedef unsigned short u16;
typedef __attribute__((ext_vector_type(8))) short short8;
typedef __attribute__((ext_vector_type(4))) float float4v;

#define M_TOK   16384
#define DIM     1024
#define HID     4096

// ---------- helpers ----------

__device__ __forceinline__ u16 f2bf(float f) {
    union { float f; unsigned u; } v; v.f = f;
    unsigned r = v.u + 0x7fffu + ((v.u >> 16) & 1u);   // RNE
    return (u16)(r >> 16);
}

__device__ __forceinline__ void gload_lds16(const u16* g, u16* l) {
    __builtin_amdgcn_global_load_lds(
        (const __attribute__((address_space(1))) void*)g,
        (__attribute__((address_space(3))) void*)l, 16, 0, 0);
}

// ---------- fused prologue kernel ----------
// blocks [0, HID)           : build W1 row b   (adapter T inlined)
// blocks [HID, HID+DIM)     : build W2 row b-HID
// blocks [HID+DIM, +16384)  : cvt x -> bf16

__global__ __launch_bounds__(256) void prologue_kernel(
    const float* __restrict__ x, const float* __restrict__ w_fc,
    const float* __restrict__ w_proj, const float* __restrict__ u,
    const float* __restrict__ fb, const float* __restrict__ v,
    const float* __restrict__ gate,
    u16* __restrict__ Xb, u16* __restrict__ W1, u16* __restrict__ W2) {
    const int b = blockIdx.x, tid = threadIdx.x;
    __shared__ float red[4];

    if (b < HID) {
        // ---- build_w1, row = b ----
        const int row = b;
        float s = 0.f;
#pragma unroll
        for (int jj = 0; jj < 4; jj++) s += fabsf(w_fc[row * 1024 + tid + jj * 256]);
#pragma unroll
        for (int o = 32; o > 0; o >>= 1) s += __shfl_down(s, o, 64);
        if ((tid & 63) == 0) red[tid >> 6] = s;
        __syncthreads();
        const float scale = fmaxf((red[0] + red[1] + red[2] + red[3]) * (1.f / 1024.f), 1e-5f);
        const float g = gate[0];
        float t[16];
#pragma unroll
        for (int r = 0; r < 16; r++) t[r] = 0.f;
#pragma unroll
        for (int k = 0; k < 16; k++) {
            const float uk = u[row * 16 + k];
#pragma unroll
            for (int r = 0; r < 16; r++) t[r] += uk * fb[k * 16 + r];
        }
#pragma unroll
        for (int jj = 0; jj < 4; jj++) {
            const int j = tid + jj * 256;
            const float wv = w_fc[row * 1024 + j];
            float tern = rintf(wv / scale);
            tern = fminf(1.f, fmaxf(-1.f, tern));
            float ad = 0.f;
#pragma unroll
            for (int r = 0; r < 16; r++) ad += t[r] * v[r * 1024 + j];
            W1[row * 1024 + j] = f2bf(tern * scale + g * ad);
        }
    } else if (b < HID + DIM) {
        // ---- build_w2, row = b - HID ----
        const int row = b - HID;
        float s = 0.f;
#pragma unroll
        for (int jj = 0; jj < 16; jj++) s += fabsf(w_proj[row * 4096 + tid + jj * 256]);
#pragma unroll
        for (int o = 32; o > 0; o >>= 1) s += __shfl_down(s, o, 64);
        if ((tid & 63) == 0) red[tid >> 6] = s;
        __syncthreads();
        const float scale = fmaxf((red[0] + red[1] + red[2] + red[3]) * (1.f / 4096.f), 1e-5f);
#pragma unroll
        for (int jj = 0; jj < 16; jj++) {
            const int j = tid + jj * 256;
            float tern = rintf(w_proj[row * 4096 + j] / scale);
            tern = fminf(1.f, fmaxf(-1.f, tern));
            W2[row * 4096 + j] = f2bf(tern * scale);
        }
    } else {
        // ---- cvt_x ----
        const int i = (b - (HID + DIM)) * 1024 + tid * 4;
        float4 vv = *reinterpret_cast<const float4*>(x + i);
        ushort4 o;
        o.x = f2bf(vv.x); o.y = f2bf(vv.y); o.z = f2bf(vv.z); o.w = f2bf(vv.w);
        *reinterpret_cast<ushort4*>(Xb + i) = o;
    }
}

// ---------- GEMM: C[M,N] = A[M,K] @ B[N,K]^T (both bf16 row-major) ----------
// 256x128 block, 4 waves (2M x 2N), per-wave 128x64. BK=32. LDS: dbuf x
// (A 16KB + B 8KB) = 48 KiB -> 3 blocks/CU (12 waves, 3/SIMD).
//
// LDS tile: [rows][32 elems] as 4 chunks of 8; chunk position p of row r
// holds k-chunk p ^ ((r>>1)&3). Staging chunk q=tid+256c: row=q>>2, pos=q&3,
// k-chunk kc=(tid&3)^((tid>>3)&3) (const/thread) -> 6 gload_lds/thread/tile,
// wave-linear LDS dest (m104-safe), 64B-segment coalesced global.
// Frag read: lane(lr,quad) reads row wm|wn + 16i + lr, pos quad^((lr>>1)&3)
// -> within each 16-lane group 2-way max (free, m136).
//
// Per K-tile: STAGE(nxt) | 12 ds_read_b128 | 32 MFMA (setprio) | vmcnt(0) |
// barrier. Cross-block anti-phase (3 blocks/CU, no shared barriers) hides
// the stage latency + drain + read latency.
template <int N, int K, int EPI>
__global__ __launch_bounds__(256, 3) void gemm_t3(const u16* __restrict__ A,
                                                  const u16* __restrict__ B,
                                                  void* __restrict__ Cv) {
    constexpr int GM  = M_TOK / 256;   // 64
    constexpr int GN  = N / 128;       // 32 / 8
    constexpr int NWG = GM * GN;       // 2048 / 512 (%8==0)
    constexpr int NT  = K / 32;        // 32 / 128

    __shared__ alignas(16) u16 lds[2][12288];   // per buf: A[0,8192) B[8192,12288)

    const int tid  = threadIdx.x;
    const int wave = tid >> 6, lane = tid & 63;
    const int lr = lane & 15, quad = lane >> 4;
    const int wm = (wave >> 1) << 7;   // 0 / 128
    const int wn = (wave & 1) << 6;    // 0 / 64

    // T1 chunked-bijective XCD swizzle (NWG % 8 == 0)
    int flat = (int)blockIdx.x;
    flat = (flat & 7) * (NWG / 8) + (flat >> 3);
    const int bm = flat % GM;
    const int bn = flat / GM;

    // staging bases (k-chunk kc constant per thread)
    const int r0 = tid >> 2;                               // 0..63
    const int kc = (tid & 3) ^ ((tid >> 3) & 3);
    const u16* Ag0 = A + (size_t)(bm * 256 + r0) * K + kc * 8;
    const u16* Bg0 = B + (size_t)(bn * 128 + r0) * K + kc * 8;

    float4v acc[8][4];
#pragma unroll
    for (int i = 0; i < 8; i++)
#pragma unroll
        for (int j = 0; j < 4; j++) acc[i][j] = (float4v)0.0f;

    // fragment read offsets (u16 units): row*32 + pos*8
    const int pk = (quad ^ ((lr >> 1) & 3)) * 8;
    const int offA0 = (wm + lr) * 32 + pk;                 // + 512*i
    const int offB0 = (wn + lr) * 32 + pk;                 // + 512*j

#define CFENCE() asm volatile("" ::: "memory")
#define BARX()   do { CFENCE(); __builtin_amdgcn_s_barrier(); CFENCE(); } while (0)
#define WVM0()   asm volatile("s_waitcnt vmcnt(0)" ::: "memory")

#define STAGE(buf, k0)                                                        \
    do {                                                                      \
        u16* la_ = &lds[buf][0]; u16* lb_ = &lds[buf][8192];                  \
        _Pragma("unroll")                                                     \
        for (int c_ = 0; c_ < 4; c_++)                                        \
            gload_lds16(Ag0 + (size_t)c_ * 64 * K + (k0), la_ + (tid + 256 * c_) * 8); \
        _Pragma("unroll")                                                     \
        for (int c_ = 0; c_ < 2; c_++)                                        \
            gload_lds16(Bg0 + (size_t)c_ * 64 * K + (k0), lb_ + (tid + 256 * c_) * 8); \
    } while (0)

    // ---- prologue: tile 0 -> buf 0 ----
    STAGE(0, 0);
    WVM0();
    BARX();

#pragma unroll 1
    for (int t = 0; t < NT; ++t) {
        const int cur = t & 1;
        if (t + 1 < NT) STAGE(cur ^ 1, (t + 1) * 32);   // overwrite t-1's buf (all reads retired pre-barrier)

        const u16* As = &lds[cur][0];
        const u16* Bs = &lds[cur][8192];
        short8 Af[8], Bf[4];
#pragma unroll
        for (int i = 0; i < 8; i++)
            Af[i] = *reinterpret_cast<const short8*>(As + offA0 + 512 * i);
#pragma unroll
        for (int j = 0; j < 4; j++)
            Bf[j] = *reinterpret_cast<const short8*>(Bs + offB0 + 512 * j);

        __builtin_amdgcn_s_setprio(1);
#pragma unroll
        for (int i = 0; i < 8; i++)
#pragma unroll
            for (int j = 0; j < 4; j++)
                acc[i][j] = __builtin_amdgcn_mfma_f32_16x16x32_bf16(
                    Af[i], Bf[j], acc[i][j], 0, 0, 0);
        __builtin_amdgcn_s_setprio(0);

        if (t + 1 < NT) {
            WVM0();        // next tile's 6 DMA loads landed (issued ~full tile ago)
            BARX();        // all waves done reading buf[cur]; buf[nxt] valid
        }
    }
    WVM0();   // safety drain (nothing should be outstanding)

#undef CFENCE
#undef BARX
#undef WVM0
#undef STAGE

    // ---- epilogue. C/D layout: col=lane&15, row=quad*4+reg (m89/m91-verified) ----
    const int row0 = bm * 256 + wm + quad * 4;
    const int col0 = bn * 128 + wn + lr;
#pragma unroll
    for (int i = 0; i < 8; i++)
#pragma unroll
        for (int j = 0; j < 4; j++) {
            const int col = col0 + j * 16;
            const float4v a = acc[i][j];
#pragma unroll
            for (int r = 0; r < 4; r++) {
                const int row = row0 + i * 16 + r;
                if (EPI == 0) {
                    const float rr = fmaxf(a[r], 0.f);
                    ((u16*)Cv)[(size_t)row * N + col] = f2bf(rr * rr);
                } else {
                    ((float*)Cv)[(size_t)row * N + col] = a[r];
                }
            }
        }
}

// ---------- launch ----------

extern "C" void kernel_launch(void* const* d_in, const int* in_sizes, int n_in,
                              void* d_out, int out_size, void* d_ws, size_t ws_size,
                              hipStream_t stream) {
    const float* x      = (const float*)d_in[0];
    const float* fast_b = (const float*)d_in[1];
    const float* w_fc   = (const float*)d_in[2];
    const float* w_proj = (const float*)d_in[3];
    const float* u      = (const float*)d_in[4];
    const float* v      = (const float*)d_in[5];
    const float* gate   = (const float*)d_in[6];
    float* out = (float*)d_out;

    char* ws = (char*)d_ws;
    u16*   Xb  = (u16*)(ws + 0);                         // 16384*1024*2 = 32 MB
    u16*   W1  = (u16*)(ws + 33554432);                  // 4096*1024*2  =  8 MB
    u16*   W2  = (u16*)(ws + 41943040);                  // 1024*4096*2  =  8 MB
    u16*   RSQ = (u16*)(ws + 50331648);                  // 16384*4096*2 = 128 MB

    // fused prologue: W1 rows | W2 rows | x conversion
    prologue_kernel<<<HID + DIM + M_TOK * DIM / (256 * 4), 256, 0, stream>>>(
        x, w_fc, w_proj, u, fast_b, v, gate, Xb, W1, W2);

    // GEMM1: (16384,1024) @ (4096,1024)^T -> relu^2 bf16 (16384,4096); 2048 wgs
    gemm_t3<HID, DIM, 0><<<dim3((M_TOK / 256) * (HID / 128)), 256, 0, stream>>>(Xb, W1, RSQ);
    // GEMM2: (16384,4096) @ (1024,4096)^T -> fp32 out (16384,1024); 512 wgs
    gemm_t3<DIM, HID, 1><<<dim3((M_TOK / 256) * (DIM / 128)), 256, 0, stream>>>(RSQ, W2, out);
}

// Round 8
// 827.416 us; speedup vs baseline: 1.2626x; 1.2626x over previous
//
#include <hip/hip_runtime.h>

// Problem constants (from reference setup_inputs):
//   x: (4,4096,1024) fp32 -> M=16384, dim=1024, hidden=4096, rank=16
//   w_fc: (4096,1024), w_proj: (1024,4096), u:(4096,16), v:(16,1024), fast_b:(16,16), gate scalar
// out: (16384,1024) fp32
//
// R5:  128^2, BK=64, 3 blocks/CU -> 179 us/gemm.
// R6/R7/R10: 256^2, 8 waves, three schedules -> all 151-157 us, MfmaUtil 37-39%
//     (1 block/CU: barrier-locked waves, no TLP to hide LDS/MFMA serialization).
// R11: 4x(128x128), 1 wave/SIMD -> 246 us. VGPR wall, zero TLP. FALSIFIED.
// R12: 256x128, 4 waves, BK=32, 48KB, ~2.4 blocks/CU -> 497 us BUT HBM-BOUND:
//     FETCH 938 MB (3.5x R10), hbm 54% peak, MfmaUtil 11%. Cause: bm-FAST
//     block mapping -> concurrent blocks per XCD all on different A-panels ->
//     no L2 reuse, L3 thrash. Anti-phase mechanism never actually tested.
// R13: R12 + bm-SLOW XCD-chunked mapping (consecutive blocks share A-panel,
//     L2-resident; B streams via L3). Traffic fixed -> co-residency test runs.

typedef unsigned short u16;
typedef __attribute__((ext_vector_type(8))) short short8;
typedef __attribute__((ext_vector_type(4))) float float4v;

#define M_TOK   16384
#define DIM     1024
#define HID     4096

// ---------- helpers ----------

__device__ __forceinline__ u16 f2bf(float f) {
    union { float f; unsigned u; } v; v.f = f;
    unsigned r = v.u + 0x7fffu + ((v.u >> 16) & 1u);   // RNE
    return (u16)(r >> 16);
}

__device__ __forceinline__ void gload_lds16(const u16* g, u16* l) {
    __builtin_amdgcn_global_load_lds(
        (const __attribute__((address_space(1))) void*)g,
        (__attribute__((address_space(3))) void*)l, 16, 0, 0);
}

// ---------- fused prologue kernel ----------
// blocks [0, HID)           : build W1 row b   (adapter T inlined)
// blocks [HID, HID+DIM)     : build W2 row b-HID
// blocks [HID+DIM, +16384)  : cvt x -> bf16

__global__ __launch_bounds__(256) void prologue_kernel(
    const float* __restrict__ x, const float* __restrict__ w_fc,
    const float* __restrict__ w_proj, const float* __restrict__ u,
    const float* __restrict__ fb, const float* __restrict__ v,
    const float* __restrict__ gate,
    u16* __restrict__ Xb, u16* __restrict__ W1, u16* __restrict__ W2) {
    const int b = blockIdx.x, tid = threadIdx.x;
    __shared__ float red[4];

    if (b < HID) {
        // ---- build_w1, row = b ----
        const int row = b;
        float s = 0.f;
#pragma unroll
        for (int jj = 0; jj < 4; jj++) s += fabsf(w_fc[row * 1024 + tid + jj * 256]);
#pragma unroll
        for (int o = 32; o > 0; o >>= 1) s += __shfl_down(s, o, 64);
        if ((tid & 63) == 0) red[tid >> 6] = s;
        __syncthreads();
        const float scale = fmaxf((red[0] + red[1] + red[2] + red[3]) * (1.f / 1024.f), 1e-5f);
        const float g = gate[0];
        float t[16];
#pragma unroll
        for (int r = 0; r < 16; r++) t[r] = 0.f;
#pragma unroll
        for (int k = 0; k < 16; k++) {
            const float uk = u[row * 16 + k];
#pragma unroll
            for (int r = 0; r < 16; r++) t[r] += uk * fb[k * 16 + r];
        }
#pragma unroll
        for (int jj = 0; jj < 4; jj++) {
            const int j = tid + jj * 256;
            const float wv = w_fc[row * 1024 + j];
            float tern = rintf(wv / scale);
            tern = fminf(1.f, fmaxf(-1.f, tern));
            float ad = 0.f;
#pragma unroll
            for (int r = 0; r < 16; r++) ad += t[r] * v[r * 1024 + j];
            W1[row * 1024 + j] = f2bf(tern * scale + g * ad);
        }
    } else if (b < HID + DIM) {
        // ---- build_w2, row = b - HID ----
        const int row = b - HID;
        float s = 0.f;
#pragma unroll
        for (int jj = 0; jj < 16; jj++) s += fabsf(w_proj[row * 4096 + tid + jj * 256]);
#pragma unroll
        for (int o = 32; o > 0; o >>= 1) s += __shfl_down(s, o, 64);
        if ((tid & 63) == 0) red[tid >> 6] = s;
        __syncthreads();
        const float scale = fmaxf((red[0] + red[1] + red[2] + red[3]) * (1.f / 4096.f), 1e-5f);
#pragma unroll
        for (int jj = 0; jj < 16; jj++) {
            const int j = tid + jj * 256;
            float tern = rintf(w_proj[row * 4096 + j] / scale);
            tern = fminf(1.f, fmaxf(-1.f, tern));
            W2[row * 4096 + j] = f2bf(tern * scale);
        }
    } else {
        // ---- cvt_x ----
        const int i = (b - (HID + DIM)) * 1024 + tid * 4;
        float4 vv = *reinterpret_cast<const float4*>(x + i);
        ushort4 o;
        o.x = f2bf(vv.x); o.y = f2bf(vv.y); o.z = f2bf(vv.z); o.w = f2bf(vv.w);
        *reinterpret_cast<ushort4*>(Xb + i) = o;
    }
}

// ---------- GEMM: C[M,N] = A[M,K] @ B[N,K]^T (both bf16 row-major) ----------
// 256x128 block, 4 waves (2M x 2N), per-wave 128x64. BK=32. LDS: dbuf x
// (A 16KB + B 8KB) = 48 KiB -> up to 3 blocks/CU (R12 measured ~2.4).
//
// Block mapping (R13): XCD-chunk then bm-SLOW: consecutive blocks within an
// XCD share bm (A-panel 512KB/2MB stays L2-resident across GN consecutive
// blocks); bn sweeps B panels (8 MB total, L3-resident). This is the R12 fix:
// bm-fast gave each concurrent block a distinct A-panel -> 938 MB HBM fetch.
//
// LDS tile: [rows][32 elems] as 4 chunks of 8; chunk position p of row r
// holds k-chunk p ^ ((r>>1)&3). Staging chunk q=tid+256c: row=q>>2, pos=q&3,
// k-chunk kc=(tid&3)^((tid>>3)&3) (const/thread) -> 6 gload_lds/thread/tile,
// wave-linear LDS dest (m104-safe), 64B-segment coalesced global.
// Frag read: lane(lr,quad) reads row wm|wn + 16i + lr, pos quad^((lr>>1)&3)
// -> conflict-free (R12 PMC: 0).
//
// Per K-tile: STAGE(nxt) | 12 ds_read_b128 | 32 MFMA (setprio) | vmcnt(0) |
// barrier. Cross-block anti-phase (independent blocks, no shared barriers)
// hides the stage latency + drain + read latency.
template <int N, int K, int EPI>
__global__ __launch_bounds__(256, 3) void gemm_t3(const u16* __restrict__ A,
                                                  const u16* __restrict__ B,
                                                  void* __restrict__ Cv) {
    constexpr int GM  = M_TOK / 256;   // 64
    constexpr int GN  = N / 128;       // 32 / 8
    constexpr int NWG = GM * GN;       // 2048 / 512 (%8==0)
    constexpr int NT  = K / 32;        // 32 / 128

    __shared__ alignas(16) u16 lds[2][12288];   // per buf: A[0,8192) B[8192,12288)

    const int tid  = threadIdx.x;
    const int wave = tid >> 6, lane = tid & 63;
    const int lr = lane & 15, quad = lane >> 4;
    const int wm = (wave >> 1) << 7;   // 0 / 128
    const int wn = (wave & 1) << 6;    // 0 / 64

    // T1 chunked XCD swizzle (NWG % 8 == 0), then bm-SLOW decode:
    // consecutive flat within an XCD share bm -> A-panel L2 reuse.
    int flat = (int)blockIdx.x;
    flat = (flat & 7) * (NWG / 8) + (flat >> 3);
    const int bm = flat / GN;
    const int bn = flat % GN;

    // staging bases (k-chunk kc constant per thread)
    const int r0 = tid >> 2;                               // 0..63
    const int kc = (tid & 3) ^ ((tid >> 3) & 3);
    const u16* Ag0 = A + (size_t)(bm * 256 + r0) * K + kc * 8;
    const u16* Bg0 = B + (size_t)(bn * 128 + r0) * K + kc * 8;

    float4v acc[8][4];
#pragma unroll
    for (int i = 0; i < 8; i++)
#pragma unroll
        for (int j = 0; j < 4; j++) acc[i][j] = (float4v)0.0f;

    // fragment read offsets (u16 units): row*32 + pos*8
    const int pk = (quad ^ ((lr >> 1) & 3)) * 8;
    const int offA0 = (wm + lr) * 32 + pk;                 // + 512*i
    const int offB0 = (wn + lr) * 32 + pk;                 // + 512*j

#define CFENCE() asm volatile("" ::: "memory")
#define BARX()   do { CFENCE(); __builtin_amdgcn_s_barrier(); CFENCE(); } while (0)
#define WVM0()   asm volatile("s_waitcnt vmcnt(0)" ::: "memory")

#define STAGE(buf, k0)                                                        \
    do {                                                                      \
        u16* la_ = &lds[buf][0]; u16* lb_ = &lds[buf][8192];                  \
        _Pragma("unroll")                                                     \
        for (int c_ = 0; c_ < 4; c_++)                                        \
            gload_lds16(Ag0 + (size_t)c_ * 64 * K + (k0), la_ + (tid + 256 * c_) * 8); \
        _Pragma("unroll")                                                     \
        for (int c_ = 0; c_ < 2; c_++)                                        \
            gload_lds16(Bg0 + (size_t)c_ * 64 * K + (k0), lb_ + (tid + 256 * c_) * 8); \
    } while (0)

    // ---- prologue: tile 0 -> buf 0 ----
    STAGE(0, 0);
    WVM0();
    BARX();

#pragma unroll 1
    for (int t = 0; t < NT; ++t) {
        const int cur = t & 1;
        if (t + 1 < NT) STAGE(cur ^ 1, (t + 1) * 32);   // overwrite t-1's buf (reads retired pre-barrier)

        const u16* As = &lds[cur][0];
        const u16* Bs = &lds[cur][8192];
        short8 Af[8], Bf[4];
#pragma unroll
        for (int i = 0; i < 8; i++)
            Af[i] = *reinterpret_cast<const short8*>(As + offA0 + 512 * i);
#pragma unroll
        for (int j = 0; j < 4; j++)
            Bf[j] = *reinterpret_cast<const short8*>(Bs + offB0 + 512 * j);

        __builtin_amdgcn_s_setprio(1);
#pragma unroll
        for (int i = 0; i < 8; i++)
#pragma unroll
            for (int j = 0; j < 4; j++)
                acc[i][j] = __builtin_amdgcn_mfma_f32_16x16x32_bf16(
                    Af[i], Bf[j], acc[i][j], 0, 0, 0);
        __builtin_amdgcn_s_setprio(0);

        if (t + 1 < NT) {
            WVM0();        // next tile's 6 DMA loads landed (issued a full tile ago)
            BARX();        // all waves done reading buf[cur]; buf[nxt] valid
        }
    }
    WVM0();   // safety drain

#undef CFENCE
#undef BARX
#undef WVM0
#undef STAGE

    // ---- epilogue. C/D layout: col=lane&15, row=quad*4+reg (m89/m91-verified) ----
    const int row0 = bm * 256 + wm + quad * 4;
    const int col0 = bn * 128 + wn + lr;
#pragma unroll
    for (int i = 0; i < 8; i++)
#pragma unroll
        for (int j = 0; j < 4; j++) {
            const int col = col0 + j * 16;
            const float4v a = acc[i][j];
#pragma unroll
            for (int r = 0; r < 4; r++) {
                const int row = row0 + i * 16 + r;
                if (EPI == 0) {
                    const float rr = fmaxf(a[r], 0.f);
                    ((u16*)Cv)[(size_t)row * N + col] = f2bf(rr * rr);
                } else {
                    ((float*)Cv)[(size_t)row * N + col] = a[r];
                }
            }
        }
}

// ---------- launch ----------

extern "C" void kernel_launch(void* const* d_in, const int* in_sizes, int n_in,
                              void* d_out, int out_size, void* d_ws, size_t ws_size,
                              hipStream_t stream) {
    const float* x      = (const float*)d_in[0];
    const float* fast_b = (const float*)d_in[1];
    const float* w_fc   = (const float*)d_in[2];
    const float* w_proj = (const float*)d_in[3];
    const float* u      = (const float*)d_in[4];
    const float* v      = (const float*)d_in[5];
    const float* gate   = (const float*)d_in[6];
    float* out = (float*)d_out;

    char* ws = (char*)d_ws;
    u16*   Xb  = (u16*)(ws + 0);                         // 16384*1024*2 = 32 MB
    u16*   W1  = (u16*)(ws + 33554432);                  // 4096*1024*2  =  8 MB
    u16*   W2  = (u16*)(ws + 41943040);                  // 1024*4096*2  =  8 MB
    u16*   RSQ = (u16*)(ws + 50331648);                  // 16384*4096*2 = 128 MB

    // fused prologue: W1 rows | W2 rows | x conversion
    prologue_kernel<<<HID + DIM + M_TOK * DIM / (256 * 4), 256, 0, stream>>>(
        x, w_fc, w_proj, u, fast_b, v, gate, Xb, W1, W2);

    // GEMM1: (16384,1024) @ (4096,1024)^T -> relu^2 bf16 (16384,4096); 2048 wgs
    gemm_t3<HID, DIM, 0><<<dim3((M_TOK / 256) * (HID / 128)), 256, 0, stream>>>(Xb, W1, RSQ);
    // GEMM2: (16384,4096) @ (1024,4096)^T -> fp32 out (16384,1024); 512 wgs
    gemm_t3<DIM, HID, 1><<<dim3((M_TOK / 256) * (DIM / 128)), 256, 0, stream>>>(RSQ, W2, out);
}

// Round 9
// 458.917 us; speedup vs baseline: 2.2764x; 1.8030x over previous
//
#include <hip/hip_runtime.h>

// Problem constants (from reference setup_inputs):
//   x: (4,4096,1024) fp32 -> M=16384, dim=1024, hidden=4096, rank=16
//   w_fc: (4096,1024), w_proj: (1024,4096), u:(4096,16), v:(16,1024), fast_b:(16,16), gate scalar
// out: (16384,1024) fp32
//
// R5:  128^2, BK=64 -> 179 us/gemm.
// R6/R7/R10: 256^2, 8 waves, three schedules -> 151-157 us/gemm, MfmaUtil 37-39%.
//     R10 (m201-faithful 8-phase, counted vmcnt) = best total 395 us.
// R11: 128x128/wave, 1 wave/SIMD -> 246 us/gemm. VGPR wall + zero TLP. FALSIFIED.
// R12: 256x128 multi-block, bm-fast -> 497 us/gemm. FETCH 938 MB (A-panel thrash).
// R13: + bm-slow -> FETCH fixed (140 MB, mechanism confirmed) but WRITE
//     exploded (~890 MB, 7-14x ideal; mechanism unresolved) -> 406 us/gemm.
//     => all geometry departures from R10 regressed; revert to R10 exactly.
// R14: R10 + ONE change: __builtin_nontemporal_store (nt, no-allocate) for
//     both epilogues. R10's FETCH was 270 MB/GEMM vs 40/136 ideal; theory:
//     the 128/64 MB output write streams allocate in L2/L3 and evict the
//     (easily resident) inputs. nt stops the eviction. Outputs are never
//     re-read in-kernel; kernel-boundary coherence covers RSQ->GEMM2.

typedef unsigned short u16;
typedef __attribute__((ext_vector_type(8))) short short8;
typedef __attribute__((ext_vector_type(4))) float float4v;

#define M_TOK   16384
#define DIM     1024
#define HID     4096

// ---------- helpers ----------

__device__ __forceinline__ u16 f2bf(float f) {
    union { float f; unsigned u; } v; v.f = f;
    unsigned r = v.u + 0x7fffu + ((v.u >> 16) & 1u);   // RNE
    return (u16)(r >> 16);
}

__device__ __forceinline__ void gload_lds16(const u16* g, u16* l) {
    __builtin_amdgcn_global_load_lds(
        (const __attribute__((address_space(1))) void*)g,
        (__attribute__((address_space(3))) void*)l, 16, 0, 0);
}

// ---------- fused prologue kernel ----------
// blocks [0, HID)           : build W1 row b   (adapter T inlined)
// blocks [HID, HID+DIM)     : build W2 row b-HID
// blocks [HID+DIM, +16384)  : cvt x -> bf16

__global__ __launch_bounds__(256) void prologue_kernel(
    const float* __restrict__ x, const float* __restrict__ w_fc,
    const float* __restrict__ w_proj, const float* __restrict__ u,
    const float* __restrict__ fb, const float* __restrict__ v,
    const float* __restrict__ gate,
    u16* __restrict__ Xb, u16* __restrict__ W1, u16* __restrict__ W2) {
    const int b = blockIdx.x, tid = threadIdx.x;
    __shared__ float red[4];

    if (b < HID) {
        // ---- build_w1, row = b ----
        const int row = b;
        float s = 0.f;
#pragma unroll
        for (int jj = 0; jj < 4; jj++) s += fabsf(w_fc[row * 1024 + tid + jj * 256]);
#pragma unroll
        for (int o = 32; o > 0; o >>= 1) s += __shfl_down(s, o, 64);
        if ((tid & 63) == 0) red[tid >> 6] = s;
        __syncthreads();
        const float scale = fmaxf((red[0] + red[1] + red[2] + red[3]) * (1.f / 1024.f), 1e-5f);
        const float g = gate[0];
        float t[16];
#pragma unroll
        for (int r = 0; r < 16; r++) t[r] = 0.f;
#pragma unroll
        for (int k = 0; k < 16; k++) {
            const float uk = u[row * 16 + k];
#pragma unroll
            for (int r = 0; r < 16; r++) t[r] += uk * fb[k * 16 + r];
        }
#pragma unroll
        for (int jj = 0; jj < 4; jj++) {
            const int j = tid + jj * 256;
            const float wv = w_fc[row * 1024 + j];
            float tern = rintf(wv / scale);
            tern = fminf(1.f, fmaxf(-1.f, tern));
            float ad = 0.f;
#pragma unroll
            for (int r = 0; r < 16; r++) ad += t[r] * v[r * 1024 + j];
            W1[row * 1024 + j] = f2bf(tern * scale + g * ad);
        }
    } else if (b < HID + DIM) {
        // ---- build_w2, row = b - HID ----
        const int row = b - HID;
        float s = 0.f;
#pragma unroll
        for (int jj = 0; jj < 16; jj++) s += fabsf(w_proj[row * 4096 + tid + jj * 256]);
#pragma unroll
        for (int o = 32; o > 0; o >>= 1) s += __shfl_down(s, o, 64);
        if ((tid & 63) == 0) red[tid >> 6] = s;
        __syncthreads();
        const float scale = fmaxf((red[0] + red[1] + red[2] + red[3]) * (1.f / 4096.f), 1e-5f);
#pragma unroll
        for (int jj = 0; jj < 16; jj++) {
            const int j = tid + jj * 256;
            float tern = rintf(w_proj[row * 4096 + j] / scale);
            tern = fminf(1.f, fmaxf(-1.f, tern));
            W2[row * 4096 + j] = f2bf(tern * scale);
        }
    } else {
        // ---- cvt_x ----
        const int i = (b - (HID + DIM)) * 1024 + tid * 4;
        float4 vv = *reinterpret_cast<const float4*>(x + i);
        ushort4 o;
        o.x = f2bf(vv.x); o.y = f2bf(vv.y); o.z = f2bf(vv.z); o.w = f2bf(vv.w);
        *reinterpret_cast<ushort4*>(Xb + i) = o;
    }
}

// ---------- GEMM: C[M,N] = A[M,K] @ B[N,K]^T (both bf16 row-major) ----------
// 256x256 block, 8 waves (2M x 4N), per-wave 128x64. BK=64, LDS 2x(A+B) dbuf
// = 128 KiB. Chunk q (of 2048/tile): row=q>>3, pos=q&7; pos p of row r holds
// k-chunk p^(r&7) (coalesced 128B staging, conflict-free ds_read_b128).
//
// 8-phase iteration = 2 K-tiles (t0=2it in buf0, t1=2it+1 in buf1).
// Phase p: [reads | 1 half-tile stage (2 gload_lds) | (lgkm8 if 12 reads) |
//           barrier | lgkm0 | setprio1 16 MFMA setprio0 | barrier]
//   ph1 Q0(t0): rd Alo+Blo(12); stage b1.Ah0<-t1
//   ph2 Q1(t0): rd Bhi(4);      stage b1.Ah1<-t1
//   ph3 Q2(t0): rd Ahi(8);      stage b0.Bh0<-t0+2
//   ph4 Q3(t0): rd none;        stage b0.Bh1<-t0+2; vmcnt(4|0*)
//   ph5 Q0(t1): rd Alo+Blo(12); stage b0.Ah0<-t0+2
//   ph6 Q1(t1): rd Bhi(4);      stage b0.Ah1<-t0+2
//   ph7 Q2(t1): rd Ahi(8);      stage b1.Bh0<-t1+2
//   ph8 Q3(t1): rd none;        stage b1.Bh1<-t1+2; vmcnt(4|0*)
// (*) vmcnt(4) only when THIS phase pair staged (its 4 newest in-flight
// loads are its own); final iteration -> vmcnt(0) (R9 race fix).
// Write-safety: each region's last ds_read drains at that phase's lgkm0,
// >=1 closing barrier before its re-stage. Prologue: 6 half-stages +
// vmcnt(4). NT even (16/64). All barriers block-uniform.
template <int N, int K, int EPI>
__global__ __launch_bounds__(512, 2) void gemm256(const u16* __restrict__ A,
                                                  const u16* __restrict__ B,
                                                  void* __restrict__ Cv) {
    constexpr int GM  = M_TOK / 256;   // 64
    constexpr int GN  = N / 256;
    constexpr int NWG = GM * GN;       // %8==0
    constexpr int NT  = K / 64;        // 16 / 64 (even)

    __shared__ alignas(16) u16 lds[2][2][256 * 64];   // 128 KiB

    const int tid  = threadIdx.x;
    const int wave = tid >> 6, lane = tid & 63;
    const int lr = lane & 15, quad = lane >> 4;
    const int wm = (wave >> 2) << 7;   // 0 / 128
    const int wn = (wave & 3) << 6;    // 0..192

    // T1 chunked-bijective XCD swizzle (NWG % 8 == 0)
    int flat = (int)blockIdx.x;
    flat = (flat & 7) * (NWG / 8) + (flat >> 3);
    const int bm = flat % GM;
    const int bn = flat / GM;

    // staging descriptors: 4 chunks/thread for A and B; chunks c={2h,2h+1}
    // cover rows [h*128,(h+1)*128) = half h.
    const u16* Ag[4]; const u16* Bg[4]; int qo[4];
#pragma unroll
    for (int c = 0; c < 4; c++) {
        const int q = tid + c * 512;            // 0..2047
        const int row = q >> 3, p = q & 7;
        const int kc = p ^ (row & 7);
        Ag[c] = A + (size_t)(bm * 256 + row) * K + kc * 8;
        Bg[c] = B + (size_t)(bn * 256 + row) * K + kc * 8;
        qo[c] = q * 8;
    }

    float4v acc[8][4];
#pragma unroll
    for (int i = 0; i < 8; i++)
#pragma unroll
        for (int j = 0; j < 4; j++) acc[i][j] = (float4v)0.0f;

    // fragment addressing: elem off = (wrow+lr+16*i)*64 + pk[ks]
    const int pk0 = (quad ^ (lr & 7)) * 8;          // k-step 0 chunk pos
    const int pk1 = ((4 + quad) ^ (lr & 7)) * 8;    // k-step 1 chunk pos
    const int aoff = (wm + lr) * 64;
    const int boff = (wn + lr) * 64;

#define CFENCE() asm volatile("" ::: "memory")
#define BARX()  do { CFENCE(); __builtin_amdgcn_s_barrier(); CFENCE(); } while (0)
#define WLG0()  asm volatile("s_waitcnt lgkmcnt(0)" ::: "memory")
#define WLG8()  asm volatile("s_waitcnt lgkmcnt(8)" ::: "memory")
#define WVM4()  asm volatile("s_waitcnt vmcnt(4)" ::: "memory")
#define WVM0()  asm volatile("s_waitcnt vmcnt(0)" ::: "memory")

#define STAGE_HALF(buf, mat, h, k0)                                           \
    do {                                                                      \
        u16* lp_ = &lds[buf][mat][0];                                         \
        gload_lds16(((mat) == 0 ? Ag[2*(h)]   : Bg[2*(h)])   + (k0),          \
                    lp_ + qo[2*(h)]);                                         \
        gload_lds16(((mat) == 0 ? Ag[2*(h)+1] : Bg[2*(h)+1]) + (k0),          \
                    lp_ + qo[2*(h)+1]);                                       \
    } while (0)

#define READ_A(dst, Ab, hioff)                                                \
    _Pragma("unroll")                                                         \
    for (int i_ = 0; i_ < 4; i_++) {                                          \
        dst[i_][0] = *reinterpret_cast<const short8*>((Ab) + aoff + (hioff) + 1024 * i_ + pk0); \
        dst[i_][1] = *reinterpret_cast<const short8*>((Ab) + aoff + (hioff) + 1024 * i_ + pk1); \
    }
#define READ_B(dst, Bb, hioff)                                                \
    _Pragma("unroll")                                                         \
    for (int j_ = 0; j_ < 2; j_++) {                                          \
        dst[j_][0] = *reinterpret_cast<const short8*>((Bb) + boff + (hioff) + 1024 * j_ + pk0); \
        dst[j_][1] = *reinterpret_cast<const short8*>((Bb) + boff + (hioff) + 1024 * j_ + pk1); \
    }

#define MFMA16(qr, qc, Af, Bf)                                                \
    do {                                                                      \
        __builtin_amdgcn_s_setprio(1);                                        \
        _Pragma("unroll")                                                     \
        for (int ks_ = 0; ks_ < 2; ks_++)                                     \
            _Pragma("unroll")                                                 \
            for (int i_ = 0; i_ < 4; i_++)                                    \
                _Pragma("unroll")                                             \
                for (int j_ = 0; j_ < 2; j_++)                                \
                    acc[(qr) * 4 + i_][(qc) * 2 + j_] =                       \
                        __builtin_amdgcn_mfma_f32_16x16x32_bf16(              \
                            Af[i_][ks_], Bf[j_][ks_],                         \
                            acc[(qr) * 4 + i_][(qc) * 2 + j_], 0, 0, 0);      \
        __builtin_amdgcn_s_setprio(0);                                        \
    } while (0)

    short8 Alo[4][2], Ahi[4][2], Blo[2][2], Bhi[2][2];

    // ---- staging prologue: b0 all 4 halves (t=0), b1.Bh0/Bh1 (t=1) ----
    STAGE_HALF(0, 0, 0, 0);  STAGE_HALF(0, 0, 1, 0);
    STAGE_HALF(0, 1, 0, 0);  STAGE_HALF(0, 1, 1, 0);
    STAGE_HALF(1, 1, 0, 64); STAGE_HALF(1, 1, 1, 64);
    WVM4();                     // b0 landed; b1.Bh* may remain in flight
    BARX();

    const u16* A0b = &lds[0][0][0]; const u16* B0b = &lds[0][1][0];
    const u16* A1b = &lds[1][0][0]; const u16* B1b = &lds[1][1][0];

    for (int it = 0; it < NT / 2; ++it) {
        const int t0 = 2 * it;

        // ---- ph1: Q0 of t0 ----
        READ_A(Alo, A0b, 0);
        READ_B(Blo, B0b, 0);
        STAGE_HALF(1, 0, 0, (t0 + 1) * 64);            // b1.Ah0 <- t1
        WLG8();
        BARX(); WLG0();
        MFMA16(0, 0, Alo, Blo);
        BARX();

        // ---- ph2: Q1 of t0 ----
        READ_B(Bhi, B0b, 2048);
        STAGE_HALF(1, 0, 1, (t0 + 1) * 64);            // b1.Ah1 <- t1
        BARX(); WLG0();
        MFMA16(0, 1, Alo, Bhi);
        BARX();

        // ---- ph3: Q2 of t0 ----
        READ_A(Ahi, A0b, 4096);
        if (t0 + 2 < NT) STAGE_HALF(0, 1, 0, (t0 + 2) * 64);  // b0.Bh0 <- t0+2
        BARX(); WLG0();
        MFMA16(1, 0, Ahi, Blo);
        BARX();

        // ---- ph4: Q3 of t0 (no reads) ----
        if (t0 + 2 < NT) {
            STAGE_HALF(0, 1, 1, (t0 + 2) * 64);        // b0.Bh1
            WVM4();          // newest 4 = ph3/ph4's own stages; b1 landed
        } else {
            WVM0();          // no ph3/4 stages -> must drain b1.Ah*
        }
        BARX();
        MFMA16(1, 1, Ahi, Bhi);
        BARX();

        // ---- ph5: Q0 of t1 ----
        READ_A(Alo, A1b, 0);
        READ_B(Blo, B1b, 0);
        if (t0 + 2 < NT) STAGE_HALF(0, 0, 0, (t0 + 2) * 64);  // b0.Ah0
        WLG8();
        BARX(); WLG0();
        MFMA16(0, 0, Alo, Blo);
        BARX();

        // ---- ph6: Q1 of t1 ----
        READ_B(Bhi, B1b, 2048);
        if (t0 + 2 < NT) STAGE_HALF(0, 0, 1, (t0 + 2) * 64);  // b0.Ah1
        BARX(); WLG0();
        MFMA16(0, 1, Alo, Bhi);
        BARX();

        // ---- ph7: Q2 of t1 ----
        READ_A(Ahi, A1b, 4096);
        if (t0 + 3 < NT) STAGE_HALF(1, 1, 0, (t0 + 3) * 64);  // b1.Bh0 <- t1+2
        BARX(); WLG0();
        MFMA16(1, 0, Ahi, Blo);
        BARX();

        // ---- ph8: Q3 of t1 (no reads) ----
        if (t0 + 3 < NT) {
            STAGE_HALF(1, 1, 1, (t0 + 3) * 64);        // b1.Bh1
            WVM4();          // newest 4 = ph7/ph8's own; b0(t0+2) landed
        } else {
            WVM0();          // final iteration: drain
        }
        BARX();
        MFMA16(1, 1, Ahi, Bhi);
        BARX();
    }
    WVM0();   // drain any remaining staging DMA before epilogue/exit

#undef CFENCE
#undef BARX
#undef WLG0
#undef WLG8
#undef WVM4
#undef WVM0
#undef STAGE_HALF
#undef READ_A
#undef READ_B
#undef MFMA16

    // ---- epilogue. C/D layout: col=lane&15, row=quad*4+reg (m89/m91-verified).
    // R14: nontemporal (nt, no-allocate) stores — output is never re-read in
    // this kernel; stops the write stream evicting resident inputs from L2/L3.
    const int row0 = bm * 256 + wm + quad * 4;
    const int col0 = bn * 256 + wn + lr;
#pragma unroll
    for (int qr = 0; qr < 2; qr++)
#pragma unroll
        for (int i = 0; i < 4; i++)
#pragma unroll
            for (int qc = 0; qc < 2; qc++)
#pragma unroll
                for (int j = 0; j < 2; j++) {
                    const int col = col0 + qc * 32 + j * 16;
                    const float4v a = acc[qr * 4 + i][qc * 2 + j];
#pragma unroll
                    for (int r = 0; r < 4; r++) {
                        const int row = row0 + qr * 64 + i * 16 + r;
                        if (EPI == 0) {
                            const float rr = fmaxf(a[r], 0.f);
                            __builtin_nontemporal_store(
                                f2bf(rr * rr), (u16*)Cv + (size_t)row * N + col);
                        } else {
                            __builtin_nontemporal_store(
                                a[r], (float*)Cv + (size_t)row * N + col);
                        }
                    }
                }
}

// ---------- launch ----------

extern "C" void kernel_launch(void* const* d_in, const int* in_sizes, int n_in,
                              void* d_out, int out_size, void* d_ws, size_t ws_size,
                              hipStream_t stream) {
    const float* x      = (const float*)d_in[0];
    const float* fast_b = (const float*)d_in[1];
    const float* w_fc   = (const float*)d_in[2];
    const float* w_proj = (const float*)d_in[3];
    const float* u      = (const float*)d_in[4];
    const float* v      = (const float*)d_in[5];
    const float* gate   = (const float*)d_in[6];
    float* out = (float*)d_out;

    char* ws = (char*)d_ws;
    u16*   Xb  = (u16*)(ws + 0);                         // 16384*1024*2 = 32 MB
    u16*   W1  = (u16*)(ws + 33554432);                  // 4096*1024*2  =  8 MB
    u16*   W2  = (u16*)(ws + 41943040);                  // 1024*4096*2  =  8 MB
    u16*   RSQ = (u16*)(ws + 50331648);                  // 16384*4096*2 = 128 MB

    // fused prologue: W1 rows | W2 rows | x conversion
    prologue_kernel<<<HID + DIM + M_TOK * DIM / (256 * 4), 256, 0, stream>>>(
        x, w_fc, w_proj, u, fast_b, v, gate, Xb, W1, W2);

    // GEMM1: (16384,1024) @ (4096,1024)^T -> relu^2 bf16 (16384,4096); 1024 wgs
    gemm256<HID, DIM, 0><<<dim3((M_TOK / 256) * (HID / 256)), 512, 0, stream>>>(Xb, W1, RSQ);
    // GEMM2: (16384,4096) @ (1024,4096)^T -> fp32 out (16384,1024); 256 wgs
    gemm256<DIM, HID, 1><<<dim3((M_TOK / 256) * (DIM / 256)), 512, 0, stream>>>(RSQ, W2, out);
}

// Round 11
// 411.915 us; speedup vs baseline: 2.5361x; 1.1141x over previous
//
#include <hip/hip_runtime.h>

// Problem constants (from reference setup_inputs):
//   x: (4,4096,1024) fp32 -> M=16384, dim=1024, hidden=4096, rank=16
//   w_fc: (4096,1024), w_proj: (1024,4096), u:(4096,16), v:(16,1024), fast_b:(16,16), gate scalar
// out: (16384,1024) fp32
//
// R5:  128^2, BK=64 -> 179 us/gemm.
// R6/R7/R10: 256^2, 8 waves, three schedules -> 151-157 us/gemm, MfmaUtil 37-39%.
//     R10 (m201-faithful 8-phase, counted vmcnt) = best total 395 us.
// R11-R13: geometry departures (1 wave/SIMD; 256x128 multi-block) all
//     regressed (VGPR wall / A-panel thrash / write blowup). Reverted.
// R14: nt stores on epilogue -> FALSIFIED: FETCH unchanged (eviction theory
//     wrong), WRITE doubled (nt defeats L2 write-coalescing of 32B segments),
//     MfmaUtil 39->29. Reverted to plain stores.
// R15: GEMMs = exact R10. Attack measured non-GEMM 91 us (prologue ~80 vs
//     28 BW-ideal): (a) cvt_x grid-stride 1024 blocks, 16 float4/thread
//     (was 16384 blocks x 1); (b) build_w1/w2 register-cache the weight row
//     across the reduction (row loaded ONCE, was twice with a full latency
//     round-trip after __syncthreads). Identical math/order -> same absmax.
// R16: R15 resubmission verbatim (3rd infra double-failure of the session;
//     full audit found no fault vector; R8/R9->R10 precedent says resubmit).

typedef unsigned short u16;
typedef __attribute__((ext_vector_type(8))) short short8;
typedef __attribute__((ext_vector_type(4))) float float4v;

#define M_TOK   16384
#define DIM     1024
#define HID     4096

// ---------- helpers ----------

__device__ __forceinline__ u16 f2bf(float f) {
    union { float f; unsigned u; } v; v.f = f;
    unsigned r = v.u + 0x7fffu + ((v.u >> 16) & 1u);   // RNE
    return (u16)(r >> 16);
}

__device__ __forceinline__ void gload_lds16(const u16* g, u16* l) {
    __builtin_amdgcn_global_load_lds(
        (const __attribute__((address_space(1))) void*)g,
        (__attribute__((address_space(3))) void*)l, 16, 0, 0);
}

// ---------- fused prologue kernel ----------
// blocks [0, HID)              : build W1 row b   (adapter T inlined; w row reg-cached)
// blocks [HID, HID+DIM)        : build W2 row b-HID (w row reg-cached)
// blocks [HID+DIM, HID+DIM+1024): cvt x -> bf16, grid-stride 16 float4/thread

__global__ __launch_bounds__(256) void prologue_kernel(
    const float* __restrict__ x, const float* __restrict__ w_fc,
    const float* __restrict__ w_proj, const float* __restrict__ u,
    const float* __restrict__ fb, const float* __restrict__ v,
    const float* __restrict__ gate,
    u16* __restrict__ Xb, u16* __restrict__ W1, u16* __restrict__ W2) {
    const int b = blockIdx.x, tid = threadIdx.x;
    __shared__ float red[4];

    if (b < HID) {
        // ---- build_w1, row = b ----
        const int row = b;
        float wv[4];
#pragma unroll
        for (int jj = 0; jj < 4; jj++) wv[jj] = w_fc[row * 1024 + tid + jj * 256];
        float s = 0.f;
#pragma unroll
        for (int jj = 0; jj < 4; jj++) s += fabsf(wv[jj]);   // same order as R10
#pragma unroll
        for (int o = 32; o > 0; o >>= 1) s += __shfl_down(s, o, 64);
        if ((tid & 63) == 0) red[tid >> 6] = s;
        __syncthreads();
        const float scale = fmaxf((red[0] + red[1] + red[2] + red[3]) * (1.f / 1024.f), 1e-5f);
        const float g = gate[0];
        float t[16];
#pragma unroll
        for (int r = 0; r < 16; r++) t[r] = 0.f;
#pragma unroll
        for (int k = 0; k < 16; k++) {
            const float uk = u[row * 16 + k];
#pragma unroll
            for (int r = 0; r < 16; r++) t[r] += uk * fb[k * 16 + r];
        }
#pragma unroll
        for (int jj = 0; jj < 4; jj++) {
            const int j = tid + jj * 256;
            float tern = rintf(wv[jj] / scale);
            tern = fminf(1.f, fmaxf(-1.f, tern));
            float ad = 0.f;
#pragma unroll
            for (int r = 0; r < 16; r++) ad += t[r] * v[r * 1024 + j];
            W1[row * 1024 + j] = f2bf(tern * scale + g * ad);
        }
    } else if (b < HID + DIM) {
        // ---- build_w2, row = b - HID ----
        const int row = b - HID;
        float wv[16];
#pragma unroll
        for (int jj = 0; jj < 16; jj++) wv[jj] = w_proj[row * 4096 + tid + jj * 256];
        float s = 0.f;
#pragma unroll
        for (int jj = 0; jj < 16; jj++) s += fabsf(wv[jj]);  // same order as R10
#pragma unroll
        for (int o = 32; o > 0; o >>= 1) s += __shfl_down(s, o, 64);
        if ((tid & 63) == 0) red[tid >> 6] = s;
        __syncthreads();
        const float scale = fmaxf((red[0] + red[1] + red[2] + red[3]) * (1.f / 4096.f), 1e-5f);
#pragma unroll
        for (int jj = 0; jj < 16; jj++) {
            const int j = tid + jj * 256;
            float tern = rintf(wv[jj] / scale);
            tern = fminf(1.f, fmaxf(-1.f, tern));
            W2[row * 4096 + j] = f2bf(tern * scale);
        }
    } else {
        // ---- cvt_x: grid-stride, 16 float4 per thread ----
        const int cb = b - (HID + DIM);                  // 0..1023
        const float4* xv = reinterpret_cast<const float4*>(x);
        ushort4* yv = reinterpret_cast<ushort4*>(Xb);
#pragma unroll
        for (int k = 0; k < 16; k++) {
            const int f = cb * 4096 + k * 256 + tid;     // float4 index, lane-coalesced
            float4 vv = xv[f];
            ushort4 o;
            o.x = f2bf(vv.x); o.y = f2bf(vv.y); o.z = f2bf(vv.z); o.w = f2bf(vv.w);
            yv[f] = o;
        }
    }
}

// ---------- GEMM: C[M,N] = A[M,K] @ B[N,K]^T (both bf16 row-major) ----------
// EXACT R10 kernel (plain epilogue stores). 256x256 block, 8 waves (2M x 4N),
// per-wave 128x64. BK=64, LDS 2x(A+B) dbuf = 128 KiB. Chunk q (of 2048/tile):
// row=q>>3, pos=q&7; pos p of row r holds k-chunk p^(r&7).
//
// 8-phase iteration = 2 K-tiles (t0=2it in buf0, t1=2it+1 in buf1).
//   ph1 Q0(t0): rd Alo+Blo(12); stage b1.Ah0<-t1
//   ph2 Q1(t0): rd Bhi(4);      stage b1.Ah1<-t1
//   ph3 Q2(t0): rd Ahi(8);      stage b0.Bh0<-t0+2
//   ph4 Q3(t0): rd none;        stage b0.Bh1<-t0+2; vmcnt(4|0*)
//   ph5 Q0(t1): rd Alo+Blo(12); stage b0.Ah0<-t0+2
//   ph6 Q1(t1): rd Bhi(4);      stage b0.Ah1<-t0+2
//   ph7 Q2(t1): rd Ahi(8);      stage b1.Bh0<-t1+2
//   ph8 Q3(t1): rd none;        stage b1.Bh1<-t1+2; vmcnt(4|0*)
// (*) vmcnt(4) only when THIS phase pair staged; final iteration -> vmcnt(0)
// (R9 race fix). Write-safety: each region's last ds_read drains at that
// phase's lgkm0, >=1 closing barrier before its re-stage. NT even (16/64).
template <int N, int K, int EPI>
__global__ __launch_bounds__(512, 2) void gemm256(const u16* __restrict__ A,
                                                  const u16* __restrict__ B,
                                                  void* __restrict__ Cv) {
    constexpr int GM  = M_TOK / 256;   // 64
    constexpr int GN  = N / 256;
    constexpr int NWG = GM * GN;       // %8==0
    constexpr int NT  = K / 64;        // 16 / 64 (even)

    __shared__ alignas(16) u16 lds[2][2][256 * 64];   // 128 KiB

    const int tid  = threadIdx.x;
    const int wave = tid >> 6, lane = tid & 63;
    const int lr = lane & 15, quad = lane >> 4;
    const int wm = (wave >> 2) << 7;   // 0 / 128
    const int wn = (wave & 3) << 6;    // 0..192

    // T1 chunked-bijective XCD swizzle (NWG % 8 == 0)
    int flat = (int)blockIdx.x;
    flat = (flat & 7) * (NWG / 8) + (flat >> 3);
    const int bm = flat % GM;
    const int bn = flat / GM;

    // staging descriptors: 4 chunks/thread for A and B; chunks c={2h,2h+1}
    // cover rows [h*128,(h+1)*128) = half h.
    const u16* Ag[4]; const u16* Bg[4]; int qo[4];
#pragma unroll
    for (int c = 0; c < 4; c++) {
        const int q = tid + c * 512;            // 0..2047
        const int row = q >> 3, p = q & 7;
        const int kc = p ^ (row & 7);
        Ag[c] = A + (size_t)(bm * 256 + row) * K + kc * 8;
        Bg[c] = B + (size_t)(bn * 256 + row) * K + kc * 8;
        qo[c] = q * 8;
    }

    float4v acc[8][4];
#pragma unroll
    for (int i = 0; i < 8; i++)
#pragma unroll
        for (int j = 0; j < 4; j++) acc[i][j] = (float4v)0.0f;

    // fragment addressing: elem off = (wrow+lr+16*i)*64 + pk[ks]
    const int pk0 = (quad ^ (lr & 7)) * 8;          // k-step 0 chunk pos
    const int pk1 = ((4 + quad) ^ (lr & 7)) * 8;    // k-step 1 chunk pos
    const int aoff = (wm + lr) * 64;
    const int boff = (wn + lr) * 64;

#define CFENCE() asm volatile("" ::: "memory")
#define BARX()  do { CFENCE(); __builtin_amdgcn_s_barrier(); CFENCE(); } while (0)
#define WLG0()  asm volatile("s_waitcnt lgkmcnt(0)" ::: "memory")
#define WLG8()  asm volatile("s_waitcnt lgkmcnt(8)" ::: "memory")
#define WVM4()  asm volatile("s_waitcnt vmcnt(4)" ::: "memory")
#define WVM0()  asm volatile("s_waitcnt vmcnt(0)" ::: "memory")

#define STAGE_HALF(buf, mat, h, k0)                                           \
    do {                                                                      \
        u16* lp_ = &lds[buf][mat][0];                                         \
        gload_lds16(((mat) == 0 ? Ag[2*(h)]   : Bg[2*(h)])   + (k0),          \
                    lp_ + qo[2*(h)]);                                         \
        gload_lds16(((mat) == 0 ? Ag[2*(h)+1] : Bg[2*(h)+1]) + (k0),          \
                    lp_ + qo[2*(h)+1]);                                       \
    } while (0)

#define READ_A(dst, Ab, hioff)                                                \
    _Pragma("unroll")                                                         \
    for (int i_ = 0; i_ < 4; i_++) {                                          \
        dst[i_][0] = *reinterpret_cast<const short8*>((Ab) + aoff + (hioff) + 1024 * i_ + pk0); \
        dst[i_][1] = *reinterpret_cast<const short8*>((Ab) + aoff + (hioff) + 1024 * i_ + pk1); \
    }
#define READ_B(dst, Bb, hioff)                                                \
    _Pragma("unroll")                                                         \
    for (int j_ = 0; j_ < 2; j_++) {                                          \
        dst[j_][0] = *reinterpret_cast<const short8*>((Bb) + boff + (hioff) + 1024 * j_ + pk0); \
        dst[j_][1] = *reinterpret_cast<const short8*>((Bb) + boff + (hioff) + 1024 * j_ + pk1); \
    }

#define MFMA16(qr, qc, Af, Bf)                                                \
    do {                                                                      \
        __builtin_amdgcn_s_setprio(1);                                        \
        _Pragma("unroll")                                                     \
        for (int ks_ = 0; ks_ < 2; ks_++)                                     \
            _Pragma("unroll")                                                 \
            for (int i_ = 0; i_ < 4; i_++)                                    \
                _Pragma("unroll")                                             \
                for (int j_ = 0; j_ < 2; j_++)                                \
                    acc[(qr) * 4 + i_][(qc) * 2 + j_] =                       \
                        __builtin_amdgcn_mfma_f32_16x16x32_bf16(              \
                            Af[i_][ks_], Bf[j_][ks_],                         \
                            acc[(qr) * 4 + i_][(qc) * 2 + j_], 0, 0, 0);      \
        __builtin_amdgcn_s_setprio(0);                                        \
    } while (0)

    short8 Alo[4][2], Ahi[4][2], Blo[2][2], Bhi[2][2];

    // ---- staging prologue: b0 all 4 halves (t=0), b1.Bh0/Bh1 (t=1) ----
    STAGE_HALF(0, 0, 0, 0);  STAGE_HALF(0, 0, 1, 0);
    STAGE_HALF(0, 1, 0, 0);  STAGE_HALF(0, 1, 1, 0);
    STAGE_HALF(1, 1, 0, 64); STAGE_HALF(1, 1, 1, 64);
    WVM4();                     // b0 landed; b1.Bh* may remain in flight
    BARX();

    const u16* A0b = &lds[0][0][0]; const u16* B0b = &lds[0][1][0];
    const u16* A1b = &lds[1][0][0]; const u16* B1b = &lds[1][1][0];

    for (int it = 0; it < NT / 2; ++it) {
        const int t0 = 2 * it;

        // ---- ph1: Q0 of t0 ----
        READ_A(Alo, A0b, 0);
        READ_B(Blo, B0b, 0);
        STAGE_HALF(1, 0, 0, (t0 + 1) * 64);            // b1.Ah0 <- t1
        WLG8();
        BARX(); WLG0();
        MFMA16(0, 0, Alo, Blo);
        BARX();

        // ---- ph2: Q1 of t0 ----
        READ_B(Bhi, B0b, 2048);
        STAGE_HALF(1, 0, 1, (t0 + 1) * 64);            // b1.Ah1 <- t1
        BARX(); WLG0();
        MFMA16(0, 1, Alo, Bhi);
        BARX();

        // ---- ph3: Q2 of t0 ----
        READ_A(Ahi, A0b, 4096);
        if (t0 + 2 < NT) STAGE_HALF(0, 1, 0, (t0 + 2) * 64);  // b0.Bh0 <- t0+2
        BARX(); WLG0();
        MFMA16(1, 0, Ahi, Blo);
        BARX();

        // ---- ph4: Q3 of t0 (no reads) ----
        if (t0 + 2 < NT) {
            STAGE_HALF(0, 1, 1, (t0 + 2) * 64);        // b0.Bh1
            WVM4();          // newest 4 = ph3/ph4's own stages; b1 landed
        } else {
            WVM0();          // no ph3/4 stages -> must drain b1.Ah*
        }
        BARX();
        MFMA16(1, 1, Ahi, Bhi);
        BARX();

        // ---- ph5: Q0 of t1 ----
        READ_A(Alo, A1b, 0);
        READ_B(Blo, B1b, 0);
        if (t0 + 2 < NT) STAGE_HALF(0, 0, 0, (t0 + 2) * 64);  // b0.Ah0
        WLG8();
        BARX(); WLG0();
        MFMA16(0, 0, Alo, Blo);
        BARX();

        // ---- ph6: Q1 of t1 ----
        READ_B(Bhi, B1b, 2048);
        if (t0 + 2 < NT) STAGE_HALF(0, 0, 1, (t0 + 2) * 64);  // b0.Ah1
        BARX(); WLG0();
        MFMA16(0, 1, Alo, Bhi);
        BARX();

        // ---- ph7: Q2 of t1 ----
        READ_A(Ahi, A1b, 4096);
        if (t0 + 3 < NT) STAGE_HALF(1, 1, 0, (t0 + 3) * 64);  // b1.Bh0 <- t1+2
        BARX(); WLG0();
        MFMA16(1, 0, Ahi, Blo);
        BARX();

        // ---- ph8: Q3 of t1 (no reads) ----
        if (t0 + 3 < NT) {
            STAGE_HALF(1, 1, 1, (t0 + 3) * 64);        // b1.Bh1
            WVM4();          // newest 4 = ph7/ph8's own; b0(t0+2) landed
        } else {
            WVM0();          // final iteration: drain
        }
        BARX();
        MFMA16(1, 1, Ahi, Bhi);
        BARX();
    }
    WVM0();   // drain any remaining staging DMA before epilogue/exit

#undef CFENCE
#undef BARX
#undef WLG0
#undef WLG8
#undef WVM4
#undef WVM0
#undef STAGE_HALF
#undef READ_A
#undef READ_B
#undef MFMA16

    // ---- epilogue. C/D layout: col=lane&15, row=quad*4+reg (m89/m91-verified).
    // Plain stores (R14's nt stores doubled WRITE_SIZE: no-allocate defeats
    // L2 write-coalescing of our 32B store segments).
    const int row0 = bm * 256 + wm + quad * 4;
    const int col0 = bn * 256 + wn + lr;
#pragma unroll
    for (int qr = 0; qr < 2; qr++)
#pragma unroll
        for (int i = 0; i < 4; i++)
#pragma unroll
            for (int qc = 0; qc < 2; qc++)
#pragma unroll
                for (int j = 0; j < 2; j++) {
                    const int col = col0 + qc * 32 + j * 16;
                    const float4v a = acc[qr * 4 + i][qc * 2 + j];
#pragma unroll
                    for (int r = 0; r < 4; r++) {
                        const int row = row0 + qr * 64 + i * 16 + r;
                        if (EPI == 0) {
                            const float rr = fmaxf(a[r], 0.f);
                            ((u16*)Cv)[(size_t)row * N + col] = f2bf(rr * rr);
                        } else {
                            ((float*)Cv)[(size_t)row * N + col] = a[r];
                        }
                    }
                }
}

// ---------- launch ----------

extern "C" void kernel_launch(void* const* d_in, const int* in_sizes, int n_in,
                              void* d_out, int out_size, void* d_ws, size_t ws_size,
                              hipStream_t stream) {
    const float* x      = (const float*)d_in[0];
    const float* fast_b = (const float*)d_in[1];
    const float* w_fc   = (const float*)d_in[2];
    const float* w_proj = (const float*)d_in[3];
    const float* u      = (const float*)d_in[4];
    const float* v      = (const float*)d_in[5];
    const float* gate   = (const float*)d_in[6];
    float* out = (float*)d_out;

    char* ws = (char*)d_ws;
    u16*   Xb  = (u16*)(ws + 0);                         // 16384*1024*2 = 32 MB
    u16*   W1  = (u16*)(ws + 33554432);                  // 4096*1024*2  =  8 MB
    u16*   W2  = (u16*)(ws + 41943040);                  // 1024*4096*2  =  8 MB
    u16*   RSQ = (u16*)(ws + 50331648);                  // 16384*4096*2 = 128 MB

    // fused prologue: W1 rows | W2 rows | grid-stride x conversion
    prologue_kernel<<<HID + DIM + 1024, 256, 0, stream>>>(
        x, w_fc, w_proj, u, fast_b, v, gate, Xb, W1, W2);

    // GEMM1: (16384,1024) @ (4096,1024)^T -> relu^2 bf16 (16384,4096); 1024 wgs
    gemm256<HID, DIM, 0><<<dim3((M_TOK / 256) * (HID / 256)), 512, 0, stream>>>(Xb, W1, RSQ);
    // GEMM2: (16384,4096) @ (1024,4096)^T -> fp32 out (16384,1024); 256 wgs
    gemm256<DIM, HID, 1><<<dim3((M_TOK / 256) * (DIM / 256)), 512, 0, stream>>>(RSQ, W2, out);
}